// Round 1
// baseline (408.368 us; speedup 1.0000x reference)
//
#include <hip/hip_runtime.h>
#include <math.h>

// Shapes fixed by the reference: B=4, N=4096, H=16, D=64; children = 2N.
#define BB 4
#define NN 4096
#define HH 16
#define DD 64
#define ROWS (BB * NN * HH)          // 262144 (b,n,h) rows
#define OUT_ELEMS ((size_t)ROWS * DD)

// One 16-lane group per row; each lane owns 4 contiguous floats (float4).
// r = row index over flattened (b,n,h); l = lane-in-row.
//   parent offset           : r*64 + l*4
//   child c (node 2n+c) off : ((2*bn + c)*H + h)*64 + l*4, bn = r>>4, h = r&15
//                           = ((bn<<5) + c*16 + h)*64 + l*4   (all pow2 shifts)
__global__ __launch_bounds__(256) void hsa3_kernel(
    const float* __restrict__ Qp, const float* __restrict__ Kp,
    const float* __restrict__ Vp, const float* __restrict__ Kc,
    const float* __restrict__ Vc, float* __restrict__ out,
    float* __restrict__ wout)
{
    const int tid = blockIdx.x * blockDim.x + threadIdx.x;
    const int r = tid >> 4;        // row over B*N*H
    const int l = tid & 15;        // 16 lanes per row

    const int h  = r & (HH - 1);
    const int bn = r >> 4;                         // b*N + n
    const int po = (r << 6) + (l << 2);            // parent: r*64 + l*4
    const int cb = (bn << 5) + h;                  // child-0 row in K_c/V_c
    const int c0 = (cb << 6) + (l << 2);           // *64 + l*4
    const int c1 = c0 + (HH << 6);                 // + 16*64 (child 1)

    const float4 q   = *(const float4*)(Qp + po);
    const float4 kp  = *(const float4*)(Kp + po);
    const float4 kc0 = *(const float4*)(Kc + c0);
    const float4 kc1 = *(const float4*)(Kc + c1);

    float ds = q.x*kp.x  + q.y*kp.y  + q.z*kp.z  + q.w*kp.w;
    float d0 = q.x*kc0.x + q.y*kc0.y + q.z*kc0.z + q.w*kc0.w;
    float d1 = q.x*kc1.x + q.y*kc1.y + q.z*kc1.z + q.w*kc1.w;

    // reduce across the 16-lane group (masks < 16 stay inside the group)
    #pragma unroll
    for (int m = 1; m < 16; m <<= 1) {
        ds += __shfl_xor(ds, m, 64);
        d0 += __shfl_xor(d0, m, 64);
        d1 += __shfl_xor(d1, m, 64);
    }

    const float scale = 0.125f;    // 1/sqrt(64)
    const float s0 = ds * scale, s1 = d0 * scale, s2 = d1 * scale;
    const float mx = fmaxf(s0, fmaxf(s1, s2));
    const float e0 = expf(s0 - mx), e1 = expf(s1 - mx), e2 = expf(s2 - mx);
    const float inv = 1.0f / (e0 + e1 + e2 + 1e-9f);
    const float w0 = e0 * inv, w1 = e1 * inv, w2 = e2 * inv;

    const float4 vp  = *(const float4*)(Vp + po);
    const float4 vc0 = *(const float4*)(Vc + c0);
    const float4 vc1 = *(const float4*)(Vc + c1);

    float4 o;
    o.x = w0*vp.x + w1*vc0.x + w2*vc1.x;
    o.y = w0*vp.y + w1*vc0.y + w2*vc1.y;
    o.z = w0*vp.z + w1*vc0.z + w2*vc1.z;
    o.w = w0*vp.w + w1*vc0.w + w2*vc1.w;
    *(float4*)(out + po) = o;

    // w output: [b,n,h,3] — lanes 0..2 each store one weight
    if (l < 3) {
        const float wv = (l == 0) ? w0 : ((l == 1) ? w1 : w2);
        wout[r * 3 + l] = wv;
    }
}

extern "C" void kernel_launch(void* const* d_in, const int* in_sizes, int n_in,
                              void* d_out, int out_size, void* d_ws, size_t ws_size,
                              hipStream_t stream) {
    (void)in_sizes; (void)n_in; (void)d_ws; (void)ws_size; (void)out_size;
    const float* Qp = (const float*)d_in[0];
    const float* Kp = (const float*)d_in[1];
    const float* Vp = (const float*)d_in[2];
    const float* Kc = (const float*)d_in[3];
    const float* Vc = (const float*)d_in[4];
    float* out  = (float*)d_out;
    float* wout = out + OUT_ELEMS;    // tuple: out first, then w

    const int threads = ROWS * 16;    // 4,194,304
    const int block = 256;
    const int grid = threads / block; // 16384
    hipLaunchKernelGGL(hsa3_kernel, dim3(grid), dim3(block), 0, stream,
                       Qp, Kp, Vp, Kc, Vc, out, wout);
}

// Round 2
// 405.705 us; speedup vs baseline: 1.0066x; 1.0066x over previous
//
#include <hip/hip_runtime.h>
#include <math.h>

// Shapes fixed by the reference: B=4, N=4096, H=16, D=64; children = 2N.
#define BB 4
#define NN 4096
#define HH 16
#define DD 64
#define ROWS (BB * NN * HH)          // 262144 (b,n,h) rows
#define OUT_ELEMS ((size_t)ROWS * DD)

// DPP row_ror-based 16-lane sum: v += ror(v,8); ror4; ror2; ror1.
// row_ror:N ctrl encoding = 0x120 + N. Pure VALU — no LDS pipe, no lgkmcnt.
template <int CTRL>
__device__ __forceinline__ float row_ror_add(float v) {
    int s = __builtin_amdgcn_update_dpp(0, __float_as_int(v), CTRL, 0xf, 0xf, true);
    return v + __int_as_float(s);
}
__device__ __forceinline__ float sum16(float v) {
    v = row_ror_add<0x128>(v);   // ror 8
    v = row_ror_add<0x124>(v);   // ror 4
    v = row_ror_add<0x122>(v);   // ror 2
    v = row_ror_add<0x121>(v);   // ror 1
    return v;
}

// One 16-lane group per row; each lane owns 4 contiguous floats (float4).
//   parent offset           : r*64 + l*4
//   child c (node 2n+c) off : ((bn<<5) + c*16 + h)*64 + l*4, bn=r>>4, h=r&15
__global__ __launch_bounds__(256) void hsa3_kernel(
    const float* __restrict__ Qp, const float* __restrict__ Kp,
    const float* __restrict__ Vp, const float* __restrict__ Kc,
    const float* __restrict__ Vc, float* __restrict__ out,
    float* __restrict__ wout)
{
    const int tid = blockIdx.x * blockDim.x + threadIdx.x;
    const int r = tid >> 4;        // row over B*N*H
    const int l = tid & 15;        // 16 lanes per row (== one DPP row group)

    const int h  = r & (HH - 1);
    const int bn = r >> 4;                         // b*N + n
    const int po = (r << 6) + (l << 2);            // parent: r*64 + l*4
    const int cb = (bn << 5) + h;                  // child-0 row in K_c/V_c
    const int c0 = (cb << 6) + (l << 2);           // *64 + l*4
    const int c1 = c0 + (HH << 6);                 // + 16*64 (child 1)

    // Issue ALL global loads up front — one latency window, 7 KB/wave in flight.
    const float4 q   = *(const float4*)(Qp + po);
    const float4 kp  = *(const float4*)(Kp + po);
    const float4 kc0 = *(const float4*)(Kc + c0);
    const float4 kc1 = *(const float4*)(Kc + c1);
    const float4 vp  = *(const float4*)(Vp + po);
    const float4 vc0 = *(const float4*)(Vc + c0);
    const float4 vc1 = *(const float4*)(Vc + c1);

    float ds = q.x*kp.x  + q.y*kp.y  + q.z*kp.z  + q.w*kp.w;
    float d0 = q.x*kc0.x + q.y*kc0.y + q.z*kc0.z + q.w*kc0.w;
    float d1 = q.x*kc1.x + q.y*kc1.y + q.z*kc1.z + q.w*kc1.w;

    // 16-lane reduction entirely in the VALU pipe (DPP row_ror)
    ds = sum16(ds);
    d0 = sum16(d0);
    d1 = sum16(d1);

    const float scale = 0.125f;            // 1/sqrt(64)
    const float L2E   = 1.44269504088896f; // log2(e)
    const float s0 = ds * scale, s1 = d0 * scale, s2 = d1 * scale;
    const float mx = fmaxf(s0, fmaxf(s1, s2));
    const float e0 = exp2f((s0 - mx) * L2E);
    const float e1 = exp2f((s1 - mx) * L2E);
    const float e2 = exp2f((s2 - mx) * L2E);
    const float inv = __builtin_amdgcn_rcpf(e0 + e1 + e2 + 1e-9f);
    const float w0 = e0 * inv, w1 = e1 * inv, w2 = e2 * inv;

    float4 o;
    o.x = w0*vp.x + w1*vc0.x + w2*vc1.x;
    o.y = w0*vp.y + w1*vc0.y + w2*vc1.y;
    o.z = w0*vp.z + w1*vc0.z + w2*vc1.z;
    o.w = w0*vp.w + w1*vc0.w + w2*vc1.w;
    *(float4*)(out + po) = o;

    // w output: [b,n,h,3] — lanes 0..2 each store one weight
    if (l < 3) {
        const float wv = (l == 0) ? w0 : ((l == 1) ? w1 : w2);
        wout[r * 3 + l] = wv;
    }
}

extern "C" void kernel_launch(void* const* d_in, const int* in_sizes, int n_in,
                              void* d_out, int out_size, void* d_ws, size_t ws_size,
                              hipStream_t stream) {
    (void)in_sizes; (void)n_in; (void)d_ws; (void)ws_size; (void)out_size;
    const float* Qp = (const float*)d_in[0];
    const float* Kp = (const float*)d_in[1];
    const float* Vp = (const float*)d_in[2];
    const float* Kc = (const float*)d_in[3];
    const float* Vc = (const float*)d_in[4];
    float* out  = (float*)d_out;
    float* wout = out + OUT_ELEMS;    // tuple: out first, then w

    const int threads = ROWS * 16;    // 4,194,304
    const int block = 256;
    const int grid = threads / block; // 16384
    hipLaunchKernelGGL(hsa3_kernel, dim3(grid), dim3(block), 0, stream,
                       Qp, Kp, Vp, Kc, Vc, out, wout);
}

// Round 3
// 394.022 us; speedup vs baseline: 1.0364x; 1.0297x over previous
//
#include <hip/hip_runtime.h>
#include <math.h>

// Shapes fixed by the reference: B=4, N=4096, H=16, D=64; children = 2N.
#define BB 4
#define NN 4096
#define HH 16
#define DD 64
#define ROWS (BB * NN * HH)          // 262144 (b,n,h) rows
#define OUT_ELEMS ((size_t)ROWS * DD)
#define G 2                          // rows per 16-lane group
#define GROUPS (ROWS / G)            // 131072 groups, grid-strided row pairs
#define BLOCK 256

typedef float f4 __attribute__((ext_vector_type(4)));

// DPP row_ror 16-lane butterfly sum (result in all 16 lanes). Pure VALU.
template <int CTRL>
__device__ __forceinline__ float row_ror_add(float v) {
    int s = __builtin_amdgcn_update_dpp(0, __float_as_int(v), CTRL, 0xf, 0xf, true);
    return v + __int_as_float(s);
}
__device__ __forceinline__ float sum16(float v) {
    v = row_ror_add<0x128>(v);   // ror 8
    v = row_ror_add<0x124>(v);   // ror 4
    v = row_ror_add<0x122>(v);   // ror 2
    v = row_ror_add<0x121>(v);   // ror 1
    return v;
}
__device__ __forceinline__ float dot4(f4 a, f4 b) {
    return a.x*b.x + a.y*b.y + a.z*b.z + a.w*b.w;
}
__device__ __forceinline__ f4 ntload(const float* p) {
    return __builtin_nontemporal_load((const f4*)p);
}

// One 16-lane group handles rows {gid, gid+GROUPS}. Grid-stride keeps every
// load instruction contiguous across the wave (adjacent groups -> adjacent
// rows at each unroll step). All 14 loads are issued before any wait; V
// first so it rides out the reduction+softmax latency.
__global__ __launch_bounds__(BLOCK) void hsa3_kernel(
    const float* __restrict__ Qp, const float* __restrict__ Kp,
    const float* __restrict__ Vp, const float* __restrict__ Kc,
    const float* __restrict__ Vc, float* __restrict__ out,
    float* __restrict__ wout)
{
    const int tid = blockIdx.x * BLOCK + threadIdx.x;
    const int gid = tid >> 4;
    const int l   = tid & 15;
    const int l4  = l << 2;

    const int r0 = gid;
    const int r1 = gid + GROUPS;

    // parent offsets: r*64 + l*4
    const int po0 = (r0 << 6) + l4;
    const int po1 = (r1 << 6) + l4;
    // child offsets: ((bn<<5) + h)*64 + l*4 ; +16*64 for child 1
    const int cb0 = (((r0 >> 4) << 5) + (r0 & 15));
    const int cb1 = (((r1 >> 4) << 5) + (r1 & 15));
    const int c00 = (cb0 << 6) + l4;
    const int c10 = c00 + (HH << 6);
    const int c01 = (cb1 << 6) + l4;
    const int c11 = c01 + (HH << 6);

    // ---- 14 loads, all in flight before first use (V first) ----
    const f4 vp0  = ntload(Vp + po0);
    const f4 vc00 = ntload(Vc + c00);
    const f4 vc10 = ntload(Vc + c10);
    const f4 vp1  = ntload(Vp + po1);
    const f4 vc01 = ntload(Vc + c01);
    const f4 vc11 = ntload(Vc + c11);
    const f4 q0   = ntload(Qp + po0);
    const f4 kp0  = ntload(Kp + po0);
    const f4 kc00 = ntload(Kc + c00);
    const f4 kc10 = ntload(Kc + c10);
    const f4 q1   = ntload(Qp + po1);
    const f4 kp1  = ntload(Kp + po1);
    const f4 kc01 = ntload(Kc + c01);
    const f4 kc11 = ntload(Kc + c11);

    // ---- dots ----
    float dsA = dot4(q0, kp0), d0A = dot4(q0, kc00), d1A = dot4(q0, kc10);
    float dsB = dot4(q1, kp1), d0B = dot4(q1, kc01), d1B = dot4(q1, kc11);

    dsA = sum16(dsA); d0A = sum16(d0A); d1A = sum16(d1A);
    dsB = sum16(dsB); d0B = sum16(d0B); d1B = sum16(d1B);

    const float scale = 0.125f;            // 1/sqrt(64)
    const float L2E   = 1.44269504088896f; // log2(e)

    // row A softmax
    float s0 = dsA * scale, s1 = d0A * scale, s2 = d1A * scale;
    float mx = fmaxf(s0, fmaxf(s1, s2));
    float e0 = exp2f((s0 - mx) * L2E);
    float e1 = exp2f((s1 - mx) * L2E);
    float e2 = exp2f((s2 - mx) * L2E);
    float inv = __builtin_amdgcn_rcpf(e0 + e1 + e2 + 1e-9f);
    const float w0A = e0 * inv, w1A = e1 * inv, w2A = e2 * inv;

    // row B softmax
    s0 = dsB * scale; s1 = d0B * scale; s2 = d1B * scale;
    mx = fmaxf(s0, fmaxf(s1, s2));
    e0 = exp2f((s0 - mx) * L2E);
    e1 = exp2f((s1 - mx) * L2E);
    e2 = exp2f((s2 - mx) * L2E);
    inv = __builtin_amdgcn_rcpf(e0 + e1 + e2 + 1e-9f);
    const float w0B = e0 * inv, w1B = e1 * inv, w2B = e2 * inv;

    f4 oA, oB;
    oA.x = w0A*vp0.x + w1A*vc00.x + w2A*vc10.x;
    oA.y = w0A*vp0.y + w1A*vc00.y + w2A*vc10.y;
    oA.z = w0A*vp0.z + w1A*vc00.z + w2A*vc10.z;
    oA.w = w0A*vp0.w + w1A*vc00.w + w2A*vc10.w;
    oB.x = w0B*vp1.x + w1B*vc01.x + w2B*vc11.x;
    oB.y = w0B*vp1.y + w1B*vc01.y + w2B*vc11.y;
    oB.z = w0B*vp1.z + w1B*vc01.z + w2B*vc11.z;
    oB.w = w0B*vp1.w + w1B*vc01.w + w2B*vc11.w;

    __builtin_nontemporal_store(oA, (f4*)(out + po0));
    __builtin_nontemporal_store(oB, (f4*)(out + po1));

    // w output: [b,n,h,3] — lanes 0..2 store each row's weights
    if (l < 3) {
        const float wa = (l == 0) ? w0A : ((l == 1) ? w1A : w2A);
        const float wb = (l == 0) ? w0B : ((l == 1) ? w1B : w2B);
        wout[r0 * 3 + l] = wa;
        wout[r1 * 3 + l] = wb;
    }
}

extern "C" void kernel_launch(void* const* d_in, const int* in_sizes, int n_in,
                              void* d_out, int out_size, void* d_ws, size_t ws_size,
                              hipStream_t stream) {
    (void)in_sizes; (void)n_in; (void)d_ws; (void)ws_size; (void)out_size;
    const float* Qp = (const float*)d_in[0];
    const float* Kp = (const float*)d_in[1];
    const float* Vp = (const float*)d_in[2];
    const float* Kc = (const float*)d_in[3];
    const float* Vc = (const float*)d_in[4];
    float* out  = (float*)d_out;
    float* wout = out + OUT_ELEMS;    // tuple: out first, then w

    const int threads = GROUPS * 16;  // 2,097,152
    const int grid = threads / BLOCK; // 8192
    hipLaunchKernelGGL(hsa3_kernel, dim3(grid), dim3(BLOCK), 0, stream,
                       Qp, Kp, Vp, Kc, Vc, out, wout);
}